// Round 8
// baseline (388.854 us; speedup 1.0000x reference)
//
#include <hip/hip_runtime.h>

#define D_DIM 256
#define K_CODES 1024
#define T_DIM 4096
#define NCHUNK 32
#define NCHUNKS (K_CODES / NCHUNK)          // 32
#define CHUNK_BYTES 32768                   // 2 nt x 8 ks x 2 parts x 1024 B

typedef _Float16 f16x8 __attribute__((ext_vector_type(8)));
typedef float    f32x4 __attribute__((ext_vector_type(4)));

// ws layout: [0,4096): eN f32[1024]; [4096, 4096+1MiB): B-fragment image.
// Image layout: frag[c][nt][ks][part] is 1024 B = the exact 16B/lane the
// wave needs for mfma_f32_16x16x32_f16 B (code = c*32+nt*16+(lane&15),
// k = ks*32+(lane>>4)*8+j). Every device load is a coalesced 1KB dwordx4.

// --- prep 1: eN[k] = ||E[k]||^2 (fp64 accum) ---
__global__ __launch_bounds__(256) void vq_norm_kernel(const float* __restrict__ E,
                                                      float* __restrict__ eN) {
    __shared__ double wsum[4];
    const int k = blockIdx.x;
    const int tid = threadIdx.x;
    float v = E[(size_t)k * D_DIM + tid];
    double s = (double)v * (double)v;
    #pragma unroll
    for (int off = 32; off > 0; off >>= 1)
        s += __shfl_down(s, off);
    if ((tid & 63) == 0) wsum[tid >> 6] = s;
    __syncthreads();
    if (tid == 0) eN[k] = (float)((wsum[0] + wsum[1]) + (wsum[2] + wsum[3]));
}

// --- prep 2: E -> f16 hi/lo B-fragment image in lane order ---
__global__ __launch_bounds__(256) void vq_prep_e(const float* __restrict__ E,
                                                 char* __restrict__ img) {
    const int g    = blockIdx.x * 256 + threadIdx.x;   // 0..32767
    const int c    = g >> 10;
    const int nt   = (g >> 9) & 1;
    const int ks   = (g >> 6) & 7;
    const int lane = g & 63;
    const int code = c * 32 + nt * 16 + (lane & 15);
    const int k0   = ks * 32 + (lane >> 4) * 8;
    const float* src = E + (size_t)code * D_DIM + k0;
    f16x8 hi, lo;
    #pragma unroll
    for (int j = 0; j < 8; ++j) {
        float v = src[j];
        _Float16 h = (_Float16)v;
        hi[j] = h;
        lo[j] = (_Float16)(v - (float)h);
    }
    size_t off = (size_t)((c * 16 + nt * 8 + ks) * 2) * 1024 + lane * 16;
    *(f16x8*)(img + off)        = hi;
    *(f16x8*)(img + off + 1024) = lo;
}

// Single-wave blocks, zero barriers, no LDS staging: B streams from the
// L2-resident fragment image directly into registers. The LDS unit is idle;
// MFMA overlaps the vmem stream per-wave with no cross-wave coupling.
__global__ __launch_bounds__(64, 2) void vq_mfma_kernel(const float* __restrict__ z,
                                                        const float* __restrict__ E,
                                                        const float* __restrict__ eN_g,
                                                        const char* __restrict__ imgE,
                                                        float* __restrict__ out) {
    __shared__ int idx_s[32];

    const int lane = threadIdx.x;     // 0..63
    const int l15  = lane & 15;
    const int kg   = lane >> 4;       // 0..3
    const int bb   = blockIdx.x >> 7;         // 128 blocks per batch entry
    const int t0   = (blockIdx.x & 127) * 32; // 32 points per wave

    // ---- A fragments: z loaded from global (same data as rounds 2-7)
    const float* zb = z + (size_t)bb * D_DIM * T_DIM + t0;
    f16x8 a_hi[2][8], a_lo[2][8];
    #pragma unroll
    for (int s = 0; s < 2; ++s) {
        const int tcol = s * 16 + l15;
        #pragma unroll
        for (int ks = 0; ks < 8; ++ks) {
            #pragma unroll
            for (int j = 0; j < 8; ++j) {
                float v = zb[(size_t)(ks * 32 + kg * 8 + j) * T_DIM + tcol];
                _Float16 h = (_Float16)v;
                a_hi[s][ks][j] = h;
                a_lo[s][ks][j] = (_Float16)(v - (float)h);
            }
        }
    }

    float best[2][4];
    int   bestk[2][4];
    #pragma unroll
    for (int s = 0; s < 2; ++s)
        #pragma unroll
        for (int r = 0; r < 4; ++r) { best[s][r] = __builtin_huge_valf(); bestk[s][r] = 0; }

    for (int c = 0; c < NCHUNKS; ++c) {
        const char* cb = imgE + (size_t)c * CHUNK_BYTES;
        #pragma unroll 1   // keep nt rolled: bounds B-register hoisting (~16 loads max live)
        for (int nt = 0; nt < 2; ++nt) {
            const int   n  = c * NCHUNK + nt * 16 + l15;
            const float en = eN_g[n];

            f32x4 aH[2], aM[2], aL[2];
            #pragma unroll
            for (int s = 0; s < 2; ++s) {
                aH[s] = (f32x4){0.f, 0.f, 0.f, 0.f};
                aM[s] = (f32x4){0.f, 0.f, 0.f, 0.f};
                aL[s] = (f32x4){0.f, 0.f, 0.f, 0.f};
            }

            #pragma unroll
            for (int ks = 0; ks < 8; ++ks) {
                const char* fb = cb + (size_t)((nt * 8 + ks) * 2) * 1024 + lane * 16;
                f16x8 bh = *(const f16x8*)(fb);
                f16x8 bl = *(const f16x8*)(fb + 1024);
                __builtin_amdgcn_s_setprio(1);
                #pragma unroll
                for (int s = 0; s < 2; ++s)
                    aH[s] = __builtin_amdgcn_mfma_f32_16x16x32_f16(a_hi[s][ks], bh, aH[s], 0, 0, 0);
                #pragma unroll
                for (int s = 0; s < 2; ++s)
                    aM[s] = __builtin_amdgcn_mfma_f32_16x16x32_f16(a_hi[s][ks], bl, aM[s], 0, 0, 0);
                #pragma unroll
                for (int s = 0; s < 2; ++s)
                    aL[s] = __builtin_amdgcn_mfma_f32_16x16x32_f16(a_lo[s][ks], bh, aL[s], 0, 0, 0);
                __builtin_amdgcn_s_setprio(0);
            }

            #pragma unroll
            for (int s = 0; s < 2; ++s) {
                f32x4 dsum = (aH[s] + aM[s]) + aL[s];
                #pragma unroll
                for (int r = 0; r < 4; ++r) {
                    float dist = fmaf(-2.0f, dsum[r], en);
                    // strict < with ascending n == first-min tie-break (matches jnp.argmin)
                    if (dist < best[s][r]) { best[s][r] = dist; bestk[s][r] = n; }
                }
            }
        }
    }

    // ---- cross-lane argmin reduce over the 16 code-columns (bits 0-3 of lane)
    #pragma unroll
    for (int off = 1; off < 16; off <<= 1) {
        #pragma unroll
        for (int s = 0; s < 2; ++s) {
            #pragma unroll
            for (int r = 0; r < 4; ++r) {
                float od = __shfl_xor(best[s][r], off, 64);
                int   ok = __shfl_xor(bestk[s][r], off, 64);
                if (od < best[s][r] || (od == best[s][r] && ok < bestk[s][r])) {
                    best[s][r] = od; bestk[s][r] = ok;
                }
            }
        }
    }
    if (l15 == 0) {
        #pragma unroll
        for (int s = 0; s < 2; ++s)
            #pragma unroll
            for (int r = 0; r < 4; ++r)
                idx_s[s * 16 + kg * 4 + r] = bestk[s][r];
    }
    __syncthreads();   // single wave: compiles to a waitcnt, near-free

    // ---- fused gather: out[b][d][t0+tt] = E[idx[tt]][d]
    const int tt = lane & 31;
    const int dh = lane >> 5;
    const int kk = idx_s[tt];
    const float* er = E + (size_t)kk * D_DIM + dh * 128;
    float* ob = out + (size_t)bb * D_DIM * T_DIM + t0 + tt;
    #pragma unroll 8
    for (int i = 0; i < 128; ++i)
        ob[(size_t)(dh * 128 + i) * T_DIM] = er[i];
}

extern "C" void kernel_launch(void* const* d_in, const int* in_sizes, int n_in,
                              void* d_out, int out_size, void* d_ws, size_t ws_size,
                              hipStream_t stream) {
    const float* z = (const float*)d_in[0];
    const float* E = (const float*)d_in[1];
    float* out = (float*)d_out;
    float* eN  = (float*)d_ws;
    char*  img = (char*)d_ws + 4096;

    const int B = in_sizes[0] / (D_DIM * T_DIM);   // 32

    vq_norm_kernel<<<dim3(K_CODES), dim3(256), 0, stream>>>(E, eN);
    vq_prep_e<<<dim3(128), dim3(256), 0, stream>>>(E, img);

    vq_mfma_kernel<<<dim3(B * (T_DIM / 32)), dim3(64), 0, stream>>>(z, E, eN, img, out);
}

// Round 9
// 223.186 us; speedup vs baseline: 1.7423x; 1.7423x over previous
//
#include <hip/hip_runtime.h>

#define D_DIM 256
#define K_CODES 1024
#define T_DIM 4096
#define MTILE 128
#define NCHUNK 32                           // codes per chunk
#define NCHUNKS (K_CODES / NCHUNK)          // 32
#define CHUNK_BYTES 32768                   // 16 ks x 2 parts x 1024 B fragments

typedef _Float16 f16x8 __attribute__((ext_vector_type(8)));
typedef float    f32x16 __attribute__((ext_vector_type(16)));

// ws layout: [0,4096): eN f32[1024]; [4096, 4096+1 MiB): B-fragment image.
// Fragment (c, ks, part) is 1024 B in exact mfma_f32_32x32x16_f16 B lane
// order: lane holds code = c*32+(lane&31), k = ks*16+(lane>>5)*8+j.
// Staging is a linear 32 KB copy; every ds_read_b128 is a contiguous
// 1 KB wave read -> stride-1 banks, zero conflicts, no swizzle.

// --- prep 1: eN[k] = ||E[k]||^2 (fp64 accum) ---
__global__ __launch_bounds__(256) void vq_norm_kernel(const float* __restrict__ E,
                                                      float* __restrict__ eN) {
    __shared__ double wsum[4];
    const int k = blockIdx.x;
    const int tid = threadIdx.x;
    float v = E[(size_t)k * D_DIM + tid];
    double s = (double)v * (double)v;
    #pragma unroll
    for (int off = 32; off > 0; off >>= 1)
        s += __shfl_down(s, off);
    if ((tid & 63) == 0) wsum[tid >> 6] = s;
    __syncthreads();
    if (tid == 0) eN[k] = (float)((wsum[0] + wsum[1]) + (wsum[2] + wsum[3]));
}

// --- prep 2: E -> f16 hi/lo 32x32x16 B-fragment image ---
__global__ __launch_bounds__(256) void vq_prep_e(const float* __restrict__ E,
                                                 char* __restrict__ img) {
    const int g    = blockIdx.x * 256 + threadIdx.x;   // 0..32767
    const int c    = g >> 10;          // chunk 0..31
    const int ks   = (g >> 6) & 15;    // k-step 0..15
    const int lane = g & 63;
    const int code = c * NCHUNK + (lane & 31);
    const int k0   = ks * 16 + (lane >> 5) * 8;
    const float* src = E + (size_t)code * D_DIM + k0;
    f16x8 hi, lo;
    #pragma unroll
    for (int j = 0; j < 8; ++j) {
        float v = src[j];
        _Float16 h = (_Float16)v;
        hi[j] = h;
        lo[j] = (_Float16)(v - (float)h);
    }
    size_t off = (size_t)c * CHUNK_BYTES + (size_t)(ks * 2) * 1024 + lane * 16;
    *(f16x8*)(img + off)        = hi;
    *(f16x8*)(img + off + 1024) = lo;
}

__device__ __forceinline__ void stage_chunk(const char* gsrc, char* ldsdst, int tid) {
    const int lane = tid & 63;
    const int woff = (tid >> 6) << 10;   // wave*1024
    #pragma unroll
    for (int r = 0; r < 8; ++r) {
        __builtin_amdgcn_global_load_lds(
            (const __attribute__((address_space(1))) void*)(gsrc + r * 4096 + woff + (size_t)lane * 16),
            (__attribute__((address_space(3))) void*)(ldsdst + r * 4096 + woff),
            16, 0, 0);
    }
}

__global__ __launch_bounds__(256, 2) void vq_mfma_kernel(const float* __restrict__ z,
                                                         const float* __restrict__ E,
                                                         const float* __restrict__ eN_g,
                                                         const char* __restrict__ imgE,
                                                         float* __restrict__ out) {
    __shared__ __align__(16) char lds_all[2 * CHUNK_BYTES + 4096 + 512];
    char*  lds_e = lds_all;
    float* eN_s  = (float*)(lds_all + 2 * CHUNK_BYTES);
    int*   idx_s = (int*)(lds_all + 2 * CHUNK_BYTES + 4096);

    const int tid  = threadIdx.x;
    const int lane = tid & 63;
    const int w    = tid >> 6;        // wave 0..3
    const int l31  = lane & 31;
    const int khal = lane >> 5;       // k-group half 0..1
    const int bb   = blockIdx.y;
    const int t0b  = blockIdx.x * MTILE;

    // ---- A fragments for 32x32x16: wave w owns points t0b + w*32 .. +31.
    // Lane holds row = lane&31, k = ks*16 + (lane>>5)*8 + j. ~128 regs
    // (AGPR side of the unified file) -> occupancy is reg-capped at 2
    // waves/SIMD; do NOT raise launch_bounds min-waves (round-6 spill).
    const float* zb = z + (size_t)bb * D_DIM * T_DIM + t0b;
    const int tcol = w * 32 + l31;
    f16x8 a_hi[16], a_lo[16];
    #pragma unroll
    for (int ks = 0; ks < 16; ++ks) {
        #pragma unroll
        for (int j = 0; j < 8; ++j) {
            float v = zb[(size_t)(ks * 16 + khal * 8 + j) * T_DIM + tcol];
            _Float16 h = (_Float16)v;
            a_hi[ks][j] = h;
            a_lo[ks][j] = (_Float16)(v - (float)h);
        }
    }

    // ---- stage eN + first chunk
    for (int i = tid; i < K_CODES; i += 256) eN_s[i] = eN_g[i];
    stage_chunk(imgE, lds_e, tid);
    __syncthreads();

    float best[16];
    int   bestk[16];
    #pragma unroll
    for (int r = 0; r < 16; ++r) { best[r] = __builtin_huge_valf(); bestk[r] = 0; }

    for (int c = 0; c < NCHUNKS; ++c) {
        const char* ebuf = lds_e + (c & 1) * CHUNK_BYTES;
        if (c + 1 < NCHUNKS)
            stage_chunk(imgE + (size_t)(c + 1) * CHUNK_BYTES,
                        lds_e + ((c + 1) & 1) * CHUNK_BYTES, tid);

        // per-lane code norm for this chunk (same for all 16 acc rows)
        const int   n  = c * NCHUNK + l31;
        const float en = eN_s[n];

        f32x16 acc = {0.f, 0.f, 0.f, 0.f, 0.f, 0.f, 0.f, 0.f,
                      0.f, 0.f, 0.f, 0.f, 0.f, 0.f, 0.f, 0.f};

        __builtin_amdgcn_s_setprio(1);
        #pragma unroll
        for (int ks = 0; ks < 16; ++ks) {
            const char* fb = ebuf + (size_t)(ks * 2) * 1024 + lane * 16;
            f16x8 bh = *(const f16x8*)(fb);           // contiguous 1KB wave read
            f16x8 bl = *(const f16x8*)(fb + 1024);
            // all 3 passes chained into ONE accumulator (hh + lo_z*hi_e + hi_z*lo_e)
            acc = __builtin_amdgcn_mfma_f32_32x32x16_f16(a_hi[ks], bh, acc, 0, 0, 0);
            acc = __builtin_amdgcn_mfma_f32_32x32x16_f16(a_lo[ks], bh, acc, 0, 0, 0);
            acc = __builtin_amdgcn_mfma_f32_32x32x16_f16(a_hi[ks], bl, acc, 0, 0, 0);
        }
        __builtin_amdgcn_s_setprio(0);

        #pragma unroll
        for (int r = 0; r < 16; ++r) {
            float dist = fmaf(-2.0f, acc[r], en);
            // strict < with ascending n == first-min tie-break (matches jnp.argmin)
            if (dist < best[r]) { best[r] = dist; bestk[r] = n; }
        }

        __syncthreads();   // all waves done reading ebuf before it is restaged
    }

    // ---- cross-lane argmin over the 32 code-columns (within each 32-lane half)
    #pragma unroll
    for (int off = 1; off < 32; off <<= 1) {
        #pragma unroll
        for (int r = 0; r < 16; ++r) {
            float od = __shfl_xor(best[r], off, 64);
            int   ok = __shfl_xor(bestk[r], off, 64);
            if (od < best[r] || (od == best[r] && ok < bestk[r])) {
                best[r] = od; bestk[r] = ok;
            }
        }
    }
    if (l31 == 0) {
        #pragma unroll
        for (int r = 0; r < 16; ++r) {
            const int row = (r & 3) + 8 * (r >> 2) + 4 * khal;   // verified C/D map
            idx_s[w * 32 + row] = bestk[r];
        }
    }
    __syncthreads();

    // ---- fused gather: out[b][d][t0b+p] = E[idx[p]][d]
    const int p  = tid & 127;
    const int dh = tid >> 7;
    const int kk = idx_s[p];
    const float* er = E + (size_t)kk * D_DIM + dh * 128;
    float* ob = out + (size_t)bb * D_DIM * T_DIM + t0b + p;
    #pragma unroll 8
    for (int i = 0; i < 128; ++i)
        ob[(size_t)(dh * 128 + i) * T_DIM] = er[i];
}

extern "C" void kernel_launch(void* const* d_in, const int* in_sizes, int n_in,
                              void* d_out, int out_size, void* d_ws, size_t ws_size,
                              hipStream_t stream) {
    const float* z = (const float*)d_in[0];
    const float* E = (const float*)d_in[1];
    float* out = (float*)d_out;
    float* eN  = (float*)d_ws;
    char*  img = (char*)d_ws + 4096;

    const int B = in_sizes[0] / (D_DIM * T_DIM);   // 32

    vq_norm_kernel<<<dim3(K_CODES), dim3(256), 0, stream>>>(E, eN);
    vq_prep_e<<<dim3(128), dim3(256), 0, stream>>>(E, img);

    dim3 grid(T_DIM / MTILE, B);
    vq_mfma_kernel<<<grid, dim3(256), 0, stream>>>(z, E, eN, img, out);
}